// Round 1
// baseline (637.014 us; speedup 1.0000x reference)
//
#include <hip/hip_runtime.h>

#define NN 50000
#define NE 800000

// ---------------- CSR build ----------------

__global__ void hist_kernel(const int* __restrict__ dst, int* __restrict__ deg) {
    int e = blockIdx.x * 256 + threadIdx.x;
    if (e < NE) atomicAdd(&deg[dst[e]], 1);
}

__global__ void scan_kernel(const int* __restrict__ deg, int* __restrict__ rowptr,
                            int* __restrict__ cursor) {
    const int T = 1024, CH = (NN + T - 1) / T;  // 49
    int tid = threadIdx.x, base = tid * CH, sum = 0;
    for (int i = 0; i < CH; i++) { int idx = base + i; if (idx < NN) sum += deg[idx]; }
    __shared__ int sm[T];
    sm[tid] = sum; __syncthreads();
    for (int off = 1; off < T; off <<= 1) {
        int v = (tid >= off) ? sm[tid - off] : 0;
        __syncthreads();
        sm[tid] += v;
        __syncthreads();
    }
    int run = (tid == 0) ? 0 : sm[tid - 1];  // exclusive prefix of chunk sums
    for (int i = 0; i < CH; i++) {
        int idx = base + i;
        if (idx < NN) { rowptr[idx] = run; cursor[idx] = run; run += deg[idx]; }
    }
    if (tid == T - 1) rowptr[NN] = run;  // == NE
}

__global__ void fill_kernel(const int* __restrict__ src, const int* __restrict__ dst,
                            int* __restrict__ cursor, int* __restrict__ col) {
    int e = blockIdx.x * 256 + threadIdx.x;
    if (e < NE) {
        int d = dst[e];
        int pos = atomicAdd(&cursor[d], 1);
        col[pos] = src[e];
    }
}

// ---------------- pull-based mean aggregation (D=128, one wave per node) ----------------

__global__ void aggregate_kernel(const int* __restrict__ rowptr, const int* __restrict__ col,
                                 const float* __restrict__ feat, float* __restrict__ outp) {
    int wid = (blockIdx.x * blockDim.x + threadIdx.x) >> 6;  // node id
    int lane = threadIdx.x & 63;                             // lane covers 2 feats
    if (wid >= NN) return;
    int beg = rowptr[wid], end = rowptr[wid + 1];
    const float2* f2 = (const float2*)feat;
    float ax = 0.f, ay = 0.f;
    int i = beg;
    for (; i + 4 <= end; i += 4) {  // 4-way unroll: batch col loads, then 4 independent gathers
        int s0 = col[i], s1 = col[i + 1], s2 = col[i + 2], s3 = col[i + 3];
        float2 v0 = f2[s0 * 64 + lane], v1 = f2[s1 * 64 + lane];
        float2 v2 = f2[s2 * 64 + lane], v3 = f2[s3 * 64 + lane];
        ax += v0.x + v1.x + v2.x + v3.x;
        ay += v0.y + v1.y + v2.y + v3.y;
    }
    for (; i < end; i++) { int s = col[i]; float2 v = f2[s * 64 + lane]; ax += v.x; ay += v.y; }
    float inv = (end > beg) ? 1.0f / (float)(end - beg) : 0.0f;  // mean w/ max(deg,1): deg=0 -> sum=0
    ((float2*)outp)[wid * 64 + lane] = make_float2(ax * inv, ay * inv);
}

// ---------------- fused GEMM + epilogue ----------------
// C[M, BN] = [A0 | A1] @ [Wl ; Wr] + bias, then sigmoid + row-L2-norm (+ log_softmax if FINAL).
// BM=64 rows/block, full BN width per block so rows are block-local for the epilogue.
// BK=16, thread tile 4 x TN, 256 threads (tx 0..15 -> j, ty 0..15 -> m).

template <int BN, int TN, bool FINAL>
__global__ __launch_bounds__(256) void gemm_kernel(
    const float* __restrict__ A0, const float* __restrict__ A1,
    const float* __restrict__ Wl, const float* __restrict__ Wr,
    const float* __restrict__ bias, float* __restrict__ outp, int M) {
    const int BM = 64, BK = 16;
    __shared__ float sA[BK * (BM + 4)];   // [k][m], pad 4 -> 16B-aligned rows, conflict-free reads
    __shared__ float sW[BK * (BN + 4)];   // [k][j]
    int tid = threadIdx.x;
    int tx = tid & 15, ty = tid >> 4;
    int m0 = blockIdx.x * BM;

    float acc[4][TN];
#pragma unroll
    for (int i = 0; i < 4; i++)
#pragma unroll
        for (int j = 0; j < TN; j++) acc[i][j] = 0.f;

    int am = tid >> 2;        // 0..63 staged row
    int ak = (tid & 3) << 2;  // k-offset 0/4/8/12
    int wk = tid >> 4;        // 0..15 staged W row
    int wj = (tid & 15) * TN; // staged W col base

    for (int kt = 0; kt < 16; kt++) {  // virtual K=256: tiles 0..7 = (A0,Wl), 8..15 = (A1,Wr)
        const float* Asrc = (kt < 8) ? A0 : A1;
        const float* Wsrc = (kt < 8) ? Wl : Wr;
        int kb = (kt & 7) * 16;
        __syncthreads();
        // stage A (transposed into [k][m])
        int row = m0 + am;
        float4 av = (row < M) ? *(const float4*)&Asrc[(size_t)row * 128 + kb + ak]
                              : make_float4(0, 0, 0, 0);
        sA[(ak + 0) * (BM + 4) + am] = av.x;
        sA[(ak + 1) * (BM + 4) + am] = av.y;
        sA[(ak + 2) * (BM + 4) + am] = av.z;
        sA[(ak + 3) * (BM + 4) + am] = av.w;
        // stage W
#pragma unroll
        for (int c = 0; c < TN / 4; c++) {
            float4 wv = *(const float4*)&Wsrc[(size_t)(kb + wk) * BN + wj + c * 4];
            *(float4*)&sW[wk * (BN + 4) + wj + c * 4] = wv;
        }
        __syncthreads();
#pragma unroll
        for (int kk = 0; kk < BK; kk++) {
            float4 a4 = *(const float4*)&sA[kk * (BM + 4) + ty * 4];
            float a[4] = {a4.x, a4.y, a4.z, a4.w};
#pragma unroll
            for (int c = 0; c < TN / 4; c++) {
                float4 w4 = *(const float4*)&sW[kk * (BN + 4) + tx * TN + c * 4];
                float w[4] = {w4.x, w4.y, w4.z, w4.w};
#pragma unroll
                for (int mi = 0; mi < 4; mi++) {
                    acc[mi][c * 4 + 0] += a[mi] * w[0];
                    acc[mi][c * 4 + 1] += a[mi] * w[1];
                    acc[mi][c * 4 + 2] += a[mi] * w[2];
                    acc[mi][c * 4 + 3] += a[mi] * w[3];
                }
            }
        }
    }

    // epilogue: bias + sigmoid + row L2-norm; row m lives on the 16 threads sharing ty
    float ssq[4] = {0, 0, 0, 0};
#pragma unroll
    for (int mi = 0; mi < 4; mi++) {
#pragma unroll
        for (int ni = 0; ni < TN; ni++) {
            float z = acc[mi][ni] + bias[tx * TN + ni];
            float s = 1.0f / (1.0f + __expf(-z));
            acc[mi][ni] = s;
            ssq[mi] += s * s;
        }
    }
#pragma unroll
    for (int mi = 0; mi < 4; mi++) {
#pragma unroll
        for (int off = 1; off < 16; off <<= 1) ssq[mi] += __shfl_xor(ssq[mi], off, 16);
        float scale = 1.0f / fmaxf(sqrtf(ssq[mi]), 1e-12f);
#pragma unroll
        for (int ni = 0; ni < TN; ni++) acc[mi][ni] *= scale;
    }
    if (FINAL) {  // log_softmax across the row
#pragma unroll
        for (int mi = 0; mi < 4; mi++) {
            float mx = -1e30f;
#pragma unroll
            for (int ni = 0; ni < TN; ni++) mx = fmaxf(mx, acc[mi][ni]);
#pragma unroll
            for (int off = 1; off < 16; off <<= 1) mx = fmaxf(mx, __shfl_xor(mx, off, 16));
            float se = 0.f;
#pragma unroll
            for (int ni = 0; ni < TN; ni++) se += __expf(acc[mi][ni] - mx);
#pragma unroll
            for (int off = 1; off < 16; off <<= 1) se += __shfl_xor(se, off, 16);
            float lse = mx + __logf(se);
#pragma unroll
            for (int ni = 0; ni < TN; ni++) acc[mi][ni] -= lse;
        }
    }
#pragma unroll
    for (int mi = 0; mi < 4; mi++) {
        int m = m0 + ty * 4 + mi;
        if (m < M) {
#pragma unroll
            for (int c = 0; c < TN / 4; c++) {
                float4 o = make_float4(acc[mi][c * 4 + 0], acc[mi][c * 4 + 1],
                                       acc[mi][c * 4 + 2], acc[mi][c * 4 + 3]);
                *(float4*)&outp[(size_t)m * BN + tx * TN + c * 4] = o;
            }
        }
    }
}

// ---------------- launcher ----------------

extern "C" void kernel_launch(void* const* d_in, const int* in_sizes, int n_in,
                              void* d_out, int out_size, void* d_ws, size_t ws_size,
                              hipStream_t stream) {
    const float* x   = (const float*)d_in[0];
    const int*   ei  = (const int*)d_in[1];
    const float* W1l = (const float*)d_in[2];
    const float* W1r = (const float*)d_in[3];
    const float* b1  = (const float*)d_in[4];
    const float* W2l = (const float*)d_in[5];
    const float* W2r = (const float*)d_in[6];
    const float* b2  = (const float*)d_in[7];
    float* out = (float*)d_out;

    const int* src = ei;
    const int* dst = ei + NE;

    char* ws = (char*)d_ws;
    size_t off = 0;
    auto alloc = [&](size_t bytes) -> void* {
        void* p = ws + off;
        off += (bytes + 255) / 256 * 256;
        return p;
    };
    int* deg     = (int*)alloc((size_t)NN * 4);
    int* rowptr  = (int*)alloc((size_t)(NN + 1) * 4);
    int* cursor  = (int*)alloc((size_t)NN * 4);
    int* col     = (int*)alloc((size_t)NE * 4);
    float* agg   = (float*)alloc((size_t)NN * 128 * 4);
    float* h1    = (float*)alloc((size_t)NN * 128 * 4);

    // CSR build (graph identical for both layers — build once)
    hipMemsetAsync(deg, 0, (size_t)NN * 4, stream);
    hist_kernel<<<(NE + 255) / 256, 256, 0, stream>>>(dst, deg);
    scan_kernel<<<1, 1024, 0, stream>>>(deg, rowptr, cursor);
    fill_kernel<<<(NE + 255) / 256, 256, 0, stream>>>(src, dst, cursor, col);

    // layer 1: agg = mean(x over in-edges); h1 = l2norm(sigmoid(agg@W1l + x@W1r + b1))
    aggregate_kernel<<<(NN + 3) / 4, 256, 0, stream>>>(rowptr, col, x, agg);
    gemm_kernel<128, 8, false><<<(NN + 63) / 64, 256, 0, stream>>>(agg, x, W1l, W1r, b1, h1, NN);

    // layer 2: agg = mean(h1); out = log_softmax(l2norm(sigmoid(agg@W2l + h1@W2r + b2)))
    aggregate_kernel<<<(NN + 3) / 4, 256, 0, stream>>>(rowptr, col, h1, agg);
    gemm_kernel<256, 16, true><<<(NN + 63) / 64, 256, 0, stream>>>(agg, h1, W2l, W2r, b2, out, NN);
}

// Round 2
// 568.766 us; speedup vs baseline: 1.1200x; 1.1200x over previous
//
#include <hip/hip_runtime.h>

#define NN 50000
#define NE 800000

// ---------------- CSR build ----------------

__global__ void hist_kernel(const int* __restrict__ dst, int* __restrict__ deg) {
    int e = blockIdx.x * 256 + threadIdx.x;
    if (e < NE) atomicAdd(&deg[dst[e]], 1);
}

__global__ void scan_kernel(const int* __restrict__ deg, int* __restrict__ rowptr,
                            int* __restrict__ cursor) {
    const int T = 1024, CH = (NN + T - 1) / T;  // 49
    int tid = threadIdx.x, base = tid * CH, sum = 0;
    for (int i = 0; i < CH; i++) { int idx = base + i; if (idx < NN) sum += deg[idx]; }
    __shared__ int sm[T];
    sm[tid] = sum; __syncthreads();
    for (int off = 1; off < T; off <<= 1) {
        int v = (tid >= off) ? sm[tid - off] : 0;
        __syncthreads();
        sm[tid] += v;
        __syncthreads();
    }
    int run = (tid == 0) ? 0 : sm[tid - 1];  // exclusive prefix of chunk sums
    for (int i = 0; i < CH; i++) {
        int idx = base + i;
        if (idx < NN) { rowptr[idx] = run; cursor[idx] = run; run += deg[idx]; }
    }
    if (tid == T - 1) rowptr[NN] = run;  // == NE
}

__global__ void fill_kernel(const int* __restrict__ src, const int* __restrict__ dst,
                            int* __restrict__ cursor, int* __restrict__ col) {
    int e = blockIdx.x * 256 + threadIdx.x;
    if (e < NE) {
        int d = dst[e];
        int pos = atomicAdd(&cursor[d], 1);
        col[pos] = src[e];
    }
}

// ---------------- pull-based mean aggregation (D=128, one wave per node) ----------------

__global__ void aggregate_kernel(const int* __restrict__ rowptr, const int* __restrict__ col,
                                 const float* __restrict__ feat, float* __restrict__ outp) {
    int wid = (blockIdx.x * blockDim.x + threadIdx.x) >> 6;  // node id
    int lane = threadIdx.x & 63;                             // lane covers 2 feats
    if (wid >= NN) return;
    int beg = rowptr[wid], end = rowptr[wid + 1];
    const float2* f2 = (const float2*)feat;
    float ax = 0.f, ay = 0.f;
    int i = beg;
    for (; i + 4 <= end; i += 4) {  // 4-way unroll: batch col loads, then 4 independent gathers
        int s0 = col[i], s1 = col[i + 1], s2 = col[i + 2], s3 = col[i + 3];
        float2 v0 = f2[s0 * 64 + lane], v1 = f2[s1 * 64 + lane];
        float2 v2 = f2[s2 * 64 + lane], v3 = f2[s3 * 64 + lane];
        ax += v0.x + v1.x + v2.x + v3.x;
        ay += v0.y + v1.y + v2.y + v3.y;
    }
    for (; i < end; i++) { int s = col[i]; float2 v = f2[s * 64 + lane]; ax += v.x; ay += v.y; }
    float inv = (end > beg) ? 1.0f / (float)(end - beg) : 0.0f;  // mean w/ max(deg,1): deg=0 -> sum=0
    ((float2*)outp)[wid * 64 + lane] = make_float2(ax * inv, ay * inv);
}

// ---------------- fused GEMM + epilogue ----------------
// C[M, BN] = [A0 | A1] @ [Wl ; Wr] + bias, then sigmoid + row-L2-norm (+ log_softmax if FINAL).
// BM=64 rows/block, full BN width per block so rows are block-local for the epilogue.
// Thread (tx,ty): rows ty*4..+3, columns {c*64 + tx*4 .. +3} (STRIDED, not contiguous:
// per-lane LDS word offset 4*tx -> start banks {0,4,..,28}x2 = 2-way conflict = free,
// vs old tx*TN contiguous mapping -> 8-way conflict, 38% of cycles burned).

template <int BN, int TN, bool FINAL>
__global__ __launch_bounds__(256) void gemm_kernel(
    const float* __restrict__ A0, const float* __restrict__ A1,
    const float* __restrict__ Wl, const float* __restrict__ Wr,
    const float* __restrict__ bias, float* __restrict__ outp, int M) {
    const int BM = 64, BK = 16;
    const int NC = TN / 4;                // float4 column-groups per thread (2 or 4)
    __shared__ float sA[BK * (BM + 4)];   // [k][m]
    __shared__ float sW[BK * (BN + 4)];   // [k][j]
    int tid = threadIdx.x;
    int tx = tid & 15, ty = tid >> 4;
    int m0 = blockIdx.x * BM;

    float acc[4][TN];
#pragma unroll
    for (int i = 0; i < 4; i++)
#pragma unroll
        for (int j = 0; j < TN; j++) acc[i][j] = 0.f;

    int am = tid >> 2;        // 0..63 staged row
    int ak = (tid & 3) << 2;  // k-offset 0/4/8/12
    int wk = tid >> 4;        // 0..15 staged W row

    for (int kt = 0; kt < 16; kt++) {  // virtual K=256: tiles 0..7 = (A0,Wl), 8..15 = (A1,Wr)
        const float* Asrc = (kt < 8) ? A0 : A1;
        const float* Wsrc = (kt < 8) ? Wl : Wr;
        int kb = (kt & 7) * 16;
        __syncthreads();
        // stage A (transposed into [k][m])
        int row = m0 + am;
        float4 av = (row < M) ? *(const float4*)&Asrc[(size_t)row * 128 + kb + ak]
                              : make_float4(0, 0, 0, 0);
        sA[(ak + 0) * (BM + 4) + am] = av.x;
        sA[(ak + 1) * (BM + 4) + am] = av.y;
        sA[(ak + 2) * (BM + 4) + am] = av.z;
        sA[(ak + 3) * (BM + 4) + am] = av.w;
        // stage W: thread stages the same strided columns it will read
#pragma unroll
        for (int c = 0; c < NC; c++) {
            float4 wv = *(const float4*)&Wsrc[(size_t)(kb + wk) * BN + c * 64 + tx * 4];
            *(float4*)&sW[wk * (BN + 4) + c * 64 + tx * 4] = wv;
        }
        __syncthreads();
#pragma unroll
        for (int kk = 0; kk < BK; kk++) {
            float4 a4 = *(const float4*)&sA[kk * (BM + 4) + ty * 4];
            float a[4] = {a4.x, a4.y, a4.z, a4.w};
#pragma unroll
            for (int c = 0; c < NC; c++) {
                float4 w4 = *(const float4*)&sW[kk * (BN + 4) + c * 64 + tx * 4];
                float w[4] = {w4.x, w4.y, w4.z, w4.w};
#pragma unroll
                for (int mi = 0; mi < 4; mi++) {
                    acc[mi][c * 4 + 0] += a[mi] * w[0];
                    acc[mi][c * 4 + 1] += a[mi] * w[1];
                    acc[mi][c * 4 + 2] += a[mi] * w[2];
                    acc[mi][c * 4 + 3] += a[mi] * w[3];
                }
            }
        }
    }

    // epilogue: bias + sigmoid + row L2-norm; row m lives on the 16 threads sharing ty
    float ssq[4] = {0, 0, 0, 0};
#pragma unroll
    for (int mi = 0; mi < 4; mi++) {
#pragma unroll
        for (int c = 0; c < NC; c++) {
            float4 bv = *(const float4*)&bias[c * 64 + tx * 4];
            float b[4] = {bv.x, bv.y, bv.z, bv.w};
#pragma unroll
            for (int i = 0; i < 4; i++) {
                float z = acc[mi][c * 4 + i] + b[i];
                float s = 1.0f / (1.0f + __expf(-z));
                acc[mi][c * 4 + i] = s;
                ssq[mi] += s * s;
            }
        }
    }
#pragma unroll
    for (int mi = 0; mi < 4; mi++) {
#pragma unroll
        for (int off = 1; off < 16; off <<= 1) ssq[mi] += __shfl_xor(ssq[mi], off, 16);
        float scale = 1.0f / fmaxf(sqrtf(ssq[mi]), 1e-12f);
#pragma unroll
        for (int ni = 0; ni < TN; ni++) acc[mi][ni] *= scale;
    }
    if (FINAL) {  // log_softmax across the row
#pragma unroll
        for (int mi = 0; mi < 4; mi++) {
            float mx = -1e30f;
#pragma unroll
            for (int ni = 0; ni < TN; ni++) mx = fmaxf(mx, acc[mi][ni]);
#pragma unroll
            for (int off = 1; off < 16; off <<= 1) mx = fmaxf(mx, __shfl_xor(mx, off, 16));
            float se = 0.f;
#pragma unroll
            for (int ni = 0; ni < TN; ni++) se += __expf(acc[mi][ni] - mx);
#pragma unroll
            for (int off = 1; off < 16; off <<= 1) se += __shfl_xor(se, off, 16);
            float lse = mx + __logf(se);
#pragma unroll
            for (int ni = 0; ni < TN; ni++) acc[mi][ni] -= lse;
        }
    }
#pragma unroll
    for (int mi = 0; mi < 4; mi++) {
        int m = m0 + ty * 4 + mi;
        if (m < M) {
#pragma unroll
            for (int c = 0; c < NC; c++) {
                float4 o = make_float4(acc[mi][c * 4 + 0], acc[mi][c * 4 + 1],
                                       acc[mi][c * 4 + 2], acc[mi][c * 4 + 3]);
                *(float4*)&outp[(size_t)m * BN + c * 64 + tx * 4] = o;
            }
        }
    }
}

// ---------------- launcher ----------------

extern "C" void kernel_launch(void* const* d_in, const int* in_sizes, int n_in,
                              void* d_out, int out_size, void* d_ws, size_t ws_size,
                              hipStream_t stream) {
    const float* x   = (const float*)d_in[0];
    const int*   ei  = (const int*)d_in[1];
    const float* W1l = (const float*)d_in[2];
    const float* W1r = (const float*)d_in[3];
    const float* b1  = (const float*)d_in[4];
    const float* W2l = (const float*)d_in[5];
    const float* W2r = (const float*)d_in[6];
    const float* b2  = (const float*)d_in[7];
    float* out = (float*)d_out;

    const int* src = ei;
    const int* dst = ei + NE;

    char* ws = (char*)d_ws;
    size_t off = 0;
    auto alloc = [&](size_t bytes) -> void* {
        void* p = ws + off;
        off += (bytes + 255) / 256 * 256;
        return p;
    };
    int* deg     = (int*)alloc((size_t)NN * 4);
    int* rowptr  = (int*)alloc((size_t)(NN + 1) * 4);
    int* cursor  = (int*)alloc((size_t)NN * 4);
    int* col     = (int*)alloc((size_t)NE * 4);
    float* agg   = (float*)alloc((size_t)NN * 128 * 4);
    float* h1    = (float*)alloc((size_t)NN * 128 * 4);

    // CSR build (graph identical for both layers — build once)
    hipMemsetAsync(deg, 0, (size_t)NN * 4, stream);
    hist_kernel<<<(NE + 255) / 256, 256, 0, stream>>>(dst, deg);
    scan_kernel<<<1, 1024, 0, stream>>>(deg, rowptr, cursor);
    fill_kernel<<<(NE + 255) / 256, 256, 0, stream>>>(src, dst, cursor, col);

    // layer 1: agg = mean(x over in-edges); h1 = l2norm(sigmoid(agg@W1l + x@W1r + b1))
    aggregate_kernel<<<(NN + 3) / 4, 256, 0, stream>>>(rowptr, col, x, agg);
    gemm_kernel<128, 8, false><<<(NN + 63) / 64, 256, 0, stream>>>(agg, x, W1l, W1r, b1, h1, NN);

    // layer 2: agg = mean(h1); out = log_softmax(l2norm(sigmoid(agg@W2l + h1@W2r + b2)))
    aggregate_kernel<<<(NN + 3) / 4, 256, 0, stream>>>(rowptr, col, h1, agg);
    gemm_kernel<256, 16, true><<<(NN + 63) / 64, 256, 0, stream>>>(agg, h1, W2l, W2r, b2, out, NN);
}

// Round 3
// 426.918 us; speedup vs baseline: 1.4921x; 1.3323x over previous
//
#include <hip/hip_runtime.h>

#define NN 50000
#define NE 800000

// ---------------- bf16 helpers (bits-level, RNE) ----------------

__device__ __forceinline__ unsigned short f2bf(float f) {
    union { float f; unsigned u; } v; v.f = f;
    unsigned u = v.u;
    return (unsigned short)((u + 0x7fffu + ((u >> 16) & 1u)) >> 16);
}
__device__ __forceinline__ float bfu_lo(unsigned p) {  // low bf16 of packed pair
    union { unsigned u; float f; } v; v.u = p << 16; return v.f;
}
__device__ __forceinline__ float bfu_hi(unsigned p) {  // high bf16 of packed pair
    union { unsigned u; float f; } v; v.u = p & 0xffff0000u; return v.f;
}

typedef __bf16 bf16x8 __attribute__((ext_vector_type(8)));
typedef float f32x4 __attribute__((ext_vector_type(4)));
union U16 { uint4 u; bf16x8 v; };

// ---------------- CSR build ----------------

__global__ void hist_kernel(const int* __restrict__ dst, int* __restrict__ deg) {
    int e = blockIdx.x * 256 + threadIdx.x;
    if (e < NE) atomicAdd(&deg[dst[e]], 1);
}

__global__ void scan_kernel(const int* __restrict__ deg, int* __restrict__ rowptr,
                            int* __restrict__ cursor) {
    const int T = 1024, CH = (NN + T - 1) / T;  // 49
    int tid = threadIdx.x, base = tid * CH, sum = 0;
    for (int i = 0; i < CH; i++) { int idx = base + i; if (idx < NN) sum += deg[idx]; }
    __shared__ int sm[T];
    sm[tid] = sum; __syncthreads();
    for (int off = 1; off < T; off <<= 1) {
        int v = (tid >= off) ? sm[tid - off] : 0;
        __syncthreads();
        sm[tid] += v;
        __syncthreads();
    }
    int run = (tid == 0) ? 0 : sm[tid - 1];  // exclusive prefix of chunk sums
    for (int i = 0; i < CH; i++) {
        int idx = base + i;
        if (idx < NN) { rowptr[idx] = run; cursor[idx] = run; run += deg[idx]; }
    }
    if (tid == T - 1) rowptr[NN] = run;  // == NE
}

__global__ void fill_kernel(const int* __restrict__ src, const int* __restrict__ dst,
                            int* __restrict__ cursor, int* __restrict__ col) {
    int e = blockIdx.x * 256 + threadIdx.x;
    if (e < NE) {
        int d = dst[e];
        int pos = atomicAdd(&cursor[d], 1);
        col[pos] = src[e];
    }
}

// ---------------- fp32 -> bf16 cast (4 elems/thread) ----------------

__global__ void cast_bf16_kernel(const float* __restrict__ in, unsigned short* __restrict__ outp,
                                 int n4) {
    int i = blockIdx.x * 256 + threadIdx.x;
    if (i < n4) {
        float4 f = ((const float4*)in)[i];
        ushort4 o;
        o.x = f2bf(f.x); o.y = f2bf(f.y); o.z = f2bf(f.z); o.w = f2bf(f.w);
        ((ushort4*)outp)[i] = o;
    }
}

// ---------------- W pack: fp32 [Wl;Wr] (virtual K=256 x N) -> mfma B-frag layout, bf16 -----
// chunk c = nt*8 + ks (1KB each); lane holds B[k = ks*32 + (lane>>4)*8 + j][n = nt*16 + (lane&15)]
// for j=0..7, contiguous 16B per lane -> one coalesced uint4 per wave-chunk in the GEMM.

template <int N>
__global__ void pack_w_kernel(const float* __restrict__ Wl, const float* __restrict__ Wr,
                              unsigned short* __restrict__ Wp) {
    const int NT = N / 16;
    int t = blockIdx.x * 256 + threadIdx.x;  // one thread per (chunk, lane)
    if (t >= NT * 8 * 64) return;
    int lane = t & 63, c = t >> 6;
    int ks = c & 7, nt = c >> 3;
    int n = nt * 16 + (lane & 15);
    int kq = ks * 32 + (lane >> 4) * 8;
    ushort4 lohi[2];
    unsigned short tmp[8];
#pragma unroll
    for (int j = 0; j < 8; j++) {
        int k = kq + j;
        float w = (k < 128) ? Wl[(size_t)k * N + n] : Wr[(size_t)(k - 128) * N + n];
        tmp[j] = f2bf(w);
    }
    lohi[0] = make_ushort4(tmp[0], tmp[1], tmp[2], tmp[3]);
    lohi[1] = make_ushort4(tmp[4], tmp[5], tmp[6], tmp[7]);
    ((ushort4*)Wp)[(size_t)c * 128 + lane * 2 + 0] = lohi[0];
    ((ushort4*)Wp)[(size_t)c * 128 + lane * 2 + 1] = lohi[1];
}

// ---------------- pull-based mean aggregation, bf16 in / bf16 out (fp32 accum) -------------
// one wave per node; lane covers 2 feats (4B packed pair); row = 256B, fully coalesced.

__global__ void aggregate_bf_kernel(const int* __restrict__ rowptr, const int* __restrict__ col,
                                    const unsigned* __restrict__ feat2,  // [NN][64] packed pairs
                                    unsigned* __restrict__ out2) {
    int wid = (blockIdx.x * blockDim.x + threadIdx.x) >> 6;
    int lane = threadIdx.x & 63;
    if (wid >= NN) return;
    int beg = rowptr[wid], end = rowptr[wid + 1];
    float ax = 0.f, ay = 0.f;
    int i = beg;
    for (; i + 4 <= end; i += 4) {
        int s0 = col[i], s1 = col[i + 1], s2 = col[i + 2], s3 = col[i + 3];
        unsigned v0 = feat2[s0 * 64 + lane], v1 = feat2[s1 * 64 + lane];
        unsigned v2 = feat2[s2 * 64 + lane], v3 = feat2[s3 * 64 + lane];
        ax += bfu_lo(v0) + bfu_lo(v1) + bfu_lo(v2) + bfu_lo(v3);
        ay += bfu_hi(v0) + bfu_hi(v1) + bfu_hi(v2) + bfu_hi(v3);
    }
    for (; i < end; i++) {
        unsigned v = feat2[col[i] * 64 + lane];
        ax += bfu_lo(v); ay += bfu_hi(v);
    }
    float inv = (end > beg) ? 1.0f / (float)(end - beg) : 0.0f;
    unsigned o = (unsigned)f2bf(ax * inv) | ((unsigned)f2bf(ay * inv) << 16);
    out2[wid * 64 + lane] = o;
}

// ---------------- MFMA GEMM + fused epilogue (no LDS, no barriers) -------------------------
// C[M,N] = [A0|A1](bf16) @ Wp(packed bf16) + bias; sigmoid + row-L2 (+ log_softmax if FINAL).
// 256 thr = 4 waves; wave owns 16 rows x all N cols. A-frags: row-major 16B loads
// (A[m=lane&15][k=quad*8+j]); all K=256 held in 32 VGPRs, reused across NT col-tiles.
// B-frags: 1KB coalesced chunks from L2-resident Wp. C/D: row=quad*4+reg, col=lane&15 ->
// row reductions are shfl_xor width-16 within the quad.

template <int N, bool FINAL>
__global__ __launch_bounds__(256) void gemm_mfma_kernel(
    const unsigned short* __restrict__ A0, const unsigned short* __restrict__ A1,
    const unsigned short* __restrict__ Wp, const float* __restrict__ bias,
    void* __restrict__ outp, int M) {
    const int NT = N / 16;
    int tid = threadIdx.x, wave = tid >> 6, lane = tid & 63;
    int quad = lane >> 4, col = lane & 15;
    int m_base = blockIdx.x * 64 + wave * 16;
    int row = m_base + col;
    int row_ld = row < M ? row : M - 1;

    // all 8 K-step A-frags (ks 0..3 from A0, 4..7 from A1)
    bf16x8 a[8];
    const uint4* a0p = (const uint4*)(A0 + (size_t)row_ld * 128 + quad * 8);
    const uint4* a1p = (const uint4*)(A1 + (size_t)row_ld * 128 + quad * 8);
#pragma unroll
    for (int ks = 0; ks < 4; ks++) { U16 u; u.u = a0p[ks * 4]; a[ks] = u.v; }
#pragma unroll
    for (int ks = 0; ks < 4; ks++) { U16 u; u.u = a1p[ks * 4]; a[4 + ks] = u.v; }

    f32x4 acc[NT];
#pragma unroll
    for (int nt = 0; nt < NT; nt++) acc[nt] = (f32x4){0.f, 0.f, 0.f, 0.f};

    const uint4* wp = (const uint4*)Wp;  // chunk c: wp[c*64 + lane]
#pragma unroll
    for (int nt = 0; nt < NT; nt++) {
#pragma unroll
        for (int ks = 0; ks < 8; ks++) {
            U16 u; u.u = wp[(size_t)(nt * 8 + ks) * 64 + lane];
            acc[nt] = __builtin_amdgcn_mfma_f32_16x16x32_bf16(a[ks], u.v, acc[nt], 0, 0, 0);
        }
    }

    // epilogue: bias + sigmoid + row L2-norm
    float ssq[4] = {0.f, 0.f, 0.f, 0.f};
#pragma unroll
    for (int nt = 0; nt < NT; nt++) {
        float bv = bias[nt * 16 + col];
#pragma unroll
        for (int r = 0; r < 4; r++) {
            float z = acc[nt][r] + bv;
            float s = 1.0f / (1.0f + __expf(-z));
            acc[nt][r] = s;
            ssq[r] += s * s;
        }
    }
#pragma unroll
    for (int r = 0; r < 4; r++) {
#pragma unroll
        for (int off = 1; off < 16; off <<= 1) ssq[r] += __shfl_xor(ssq[r], off, 16);
        float sc = 1.0f / fmaxf(sqrtf(ssq[r]), 1e-12f);
#pragma unroll
        for (int nt = 0; nt < NT; nt++) acc[nt][r] *= sc;
    }

    if (FINAL) {  // log_softmax per row, then fp32 out
#pragma unroll
        for (int r = 0; r < 4; r++) {
            float mx = -1e30f;
#pragma unroll
            for (int nt = 0; nt < NT; nt++) mx = fmaxf(mx, acc[nt][r]);
#pragma unroll
            for (int off = 1; off < 16; off <<= 1) mx = fmaxf(mx, __shfl_xor(mx, off, 16));
            float se = 0.f;
#pragma unroll
            for (int nt = 0; nt < NT; nt++) se += __expf(acc[nt][r] - mx);
#pragma unroll
            for (int off = 1; off < 16; off <<= 1) se += __shfl_xor(se, off, 16);
            float lse = mx + __logf(se);
#pragma unroll
            for (int nt = 0; nt < NT; nt++) acc[nt][r] -= lse;
        }
        float* op = (float*)outp;
#pragma unroll
        for (int r = 0; r < 4; r++) {
            int m = m_base + quad * 4 + r;
            if (m < M) {
#pragma unroll
                for (int nt = 0; nt < NT; nt++) op[(size_t)m * N + nt * 16 + col] = acc[nt][r];
            }
        }
    } else {  // bf16 out (feeds aggregation 2 + GEMM2 A-operand)
        unsigned short* op = (unsigned short*)outp;
#pragma unroll
        for (int r = 0; r < 4; r++) {
            int m = m_base + quad * 4 + r;
            if (m < M) {
#pragma unroll
                for (int nt = 0; nt < NT; nt++)
                    op[(size_t)m * N + nt * 16 + col] = f2bf(acc[nt][r]);
            }
        }
    }
}

// ---------------- launcher ----------------

extern "C" void kernel_launch(void* const* d_in, const int* in_sizes, int n_in,
                              void* d_out, int out_size, void* d_ws, size_t ws_size,
                              hipStream_t stream) {
    const float* x   = (const float*)d_in[0];
    const int*   ei  = (const int*)d_in[1];
    const float* W1l = (const float*)d_in[2];
    const float* W1r = (const float*)d_in[3];
    const float* b1  = (const float*)d_in[4];
    const float* W2l = (const float*)d_in[5];
    const float* W2r = (const float*)d_in[6];
    const float* b2  = (const float*)d_in[7];
    float* out = (float*)d_out;

    const int* src = ei;
    const int* dst = ei + NE;

    char* ws = (char*)d_ws;
    size_t off = 0;
    auto alloc = [&](size_t bytes) -> void* {
        void* p = ws + off;
        off += (bytes + 255) / 256 * 256;
        return p;
    };
    int* deg        = (int*)alloc((size_t)NN * 4);
    int* rowptr     = (int*)alloc((size_t)(NN + 1) * 4);
    int* cursor     = (int*)alloc((size_t)NN * 4);
    int* col        = (int*)alloc((size_t)NE * 4);
    unsigned short* x_bf   = (unsigned short*)alloc((size_t)NN * 128 * 2);
    unsigned short* agg_bf = (unsigned short*)alloc((size_t)NN * 128 * 2);
    unsigned short* h1_bf  = (unsigned short*)alloc((size_t)NN * 128 * 2);
    unsigned short* W1p    = (unsigned short*)alloc((size_t)8 * 8 * 64 * 8 * 2);    // 64KB
    unsigned short* W2p    = (unsigned short*)alloc((size_t)16 * 8 * 64 * 8 * 2);   // 128KB

    // CSR build (graph identical for both layers — build once)
    hipMemsetAsync(deg, 0, (size_t)NN * 4, stream);
    hist_kernel<<<(NE + 255) / 256, 256, 0, stream>>>(dst, deg);
    scan_kernel<<<1, 1024, 0, stream>>>(deg, rowptr, cursor);
    fill_kernel<<<(NE + 255) / 256, 256, 0, stream>>>(src, dst, cursor, col);

    // prep: cast x to bf16; pack weights into B-frag layout
    cast_bf16_kernel<<<(NN * 128 / 4 + 255) / 256, 256, 0, stream>>>(x, x_bf, NN * 128 / 4);
    pack_w_kernel<128><<<(8 * 8 * 64 + 255) / 256, 256, 0, stream>>>(W1l, W1r, W1p);
    pack_w_kernel<256><<<(16 * 8 * 64 + 255) / 256, 256, 0, stream>>>(W2l, W2r, W2p);

    // layer 1
    aggregate_bf_kernel<<<(NN + 3) / 4, 256, 0, stream>>>(rowptr, col, (const unsigned*)x_bf,
                                                          (unsigned*)agg_bf);
    gemm_mfma_kernel<128, false><<<(NN + 63) / 64, 256, 0, stream>>>(agg_bf, x_bf, W1p, b1,
                                                                     h1_bf, NN);
    // layer 2
    aggregate_bf_kernel<<<(NN + 3) / 4, 256, 0, stream>>>(rowptr, col, (const unsigned*)h1_bf,
                                                          (unsigned*)agg_bf);
    gemm_mfma_kernel<256, true><<<(NN + 63) / 64, 256, 0, stream>>>(agg_bf, h1_bf, W2p, b2,
                                                                    out, NN);
}

// Round 4
// 313.048 us; speedup vs baseline: 2.0349x; 1.3637x over previous
//
#include <hip/hip_runtime.h>

#define NN 50000
#define NE 800000
#define NBLK ((NN + 255) / 256)  // 196

// ---------------- bf16 helpers (bits-level, RNE) ----------------

__device__ __forceinline__ unsigned short f2bf(float f) {
    union { float f; unsigned u; } v; v.f = f;
    unsigned u = v.u;
    return (unsigned short)((u + 0x7fffu + ((u >> 16) & 1u)) >> 16);
}
__device__ __forceinline__ float bfu_lo(unsigned p) {  // low bf16 of packed pair
    union { unsigned u; float f; } v; v.u = p << 16; return v.f;
}
__device__ __forceinline__ float bfu_hi(unsigned p) {  // high bf16 of packed pair
    union { unsigned u; float f; } v; v.u = p & 0xffff0000u; return v.f;
}

typedef __bf16 bf16x8 __attribute__((ext_vector_type(8)));
typedef float f32x4 __attribute__((ext_vector_type(4)));
union U16 { uint4 u; bf16x8 v; };

// ---------------- CSR build ----------------

__global__ void hist_kernel(const int* __restrict__ dst, int* __restrict__ deg) {
    int e = blockIdx.x * 256 + threadIdx.x;
    if (e < NE) atomicAdd(&deg[dst[e]], 1);
}

// multi-block scan, phase 1: per-block sums (196 blocks x 256)
__global__ void scan1_kernel(const int* __restrict__ deg, int* __restrict__ bsum) {
    __shared__ int sm[256];
    int tid = threadIdx.x;
    int i = blockIdx.x * 256 + tid;
    sm[tid] = (i < NN) ? deg[i] : 0;
    __syncthreads();
    for (int off = 128; off; off >>= 1) {
        if (tid < off) sm[tid] += sm[tid + off];
        __syncthreads();
    }
    if (tid == 0) bsum[blockIdx.x] = sm[0];
}

// phase 2: block b: prefix = sum(bsum[0..b)) + local exclusive scan -> rowptr/cursor
__global__ void scan2_kernel(const int* __restrict__ deg, const int* __restrict__ bsum,
                             int* __restrict__ rowptr, int* __restrict__ cursor) {
    __shared__ int sm[256];
    __shared__ int pre;
    int tid = threadIdx.x, b = blockIdx.x;
    // block-sum prefix (NBLK=196 <= 256: one element per thread, L2-hit)
    sm[tid] = (tid < b) ? bsum[tid] : 0;
    __syncthreads();
    for (int off = 128; off; off >>= 1) {
        if (tid < off) sm[tid] += sm[tid + off];
        __syncthreads();
    }
    if (tid == 0) pre = sm[0];
    __syncthreads();
    // local Hillis-Steele inclusive scan of this block's 256 degrees
    int i = b * 256 + tid;
    int v = (i < NN) ? deg[i] : 0;
    sm[tid] = v;
    __syncthreads();
    for (int off = 1; off < 256; off <<= 1) {
        int t = (tid >= off) ? sm[tid - off] : 0;
        __syncthreads();
        sm[tid] += t;
        __syncthreads();
    }
    int r = pre + sm[tid] - v;  // exclusive
    if (i < NN) { rowptr[i] = r; cursor[i] = r; }
    if (i == NN - 1) rowptr[NN] = r + v;  // == NE
}

__global__ void fill_kernel(const int* __restrict__ src, const int* __restrict__ dst,
                            int* __restrict__ cursor, int* __restrict__ col) {
    int e = blockIdx.x * 256 + threadIdx.x;
    if (e < NE) {
        int d = dst[e];
        int pos = atomicAdd(&cursor[d], 1);
        col[pos] = src[e];
    }
}

// ---------------- fp32 -> bf16 cast (4 elems/thread) ----------------

__global__ void cast_bf16_kernel(const float* __restrict__ in, unsigned short* __restrict__ outp,
                                 int n4) {
    int i = blockIdx.x * 256 + threadIdx.x;
    if (i < n4) {
        float4 f = ((const float4*)in)[i];
        ushort4 o;
        o.x = f2bf(f.x); o.y = f2bf(f.y); o.z = f2bf(f.z); o.w = f2bf(f.w);
        ((ushort4*)outp)[i] = o;
    }
}

// ---------------- W pack: fp32 [Wl;Wr] (virtual K=256 x N) -> mfma B-frag layout, bf16 -----
// chunk c = nt*8 + ks (1KB each); lane holds B[k = ks*32 + (lane>>4)*8 + j][n = nt*16 + (lane&15)]
// for j=0..7, contiguous 16B per lane -> one coalesced uint4 per wave-chunk in the GEMM.

template <int N>
__global__ void pack_w_kernel(const float* __restrict__ Wl, const float* __restrict__ Wr,
                              unsigned short* __restrict__ Wp) {
    const int NT = N / 16;
    int t = blockIdx.x * 256 + threadIdx.x;  // one thread per (chunk, lane)
    if (t >= NT * 8 * 64) return;
    int lane = t & 63, c = t >> 6;
    int ks = c & 7, nt = c >> 3;
    int n = nt * 16 + (lane & 15);
    int kq = ks * 32 + (lane >> 4) * 8;
    ushort4 lohi[2];
    unsigned short tmp[8];
#pragma unroll
    for (int j = 0; j < 8; j++) {
        int k = kq + j;
        float w = (k < 128) ? Wl[(size_t)k * N + n] : Wr[(size_t)(k - 128) * N + n];
        tmp[j] = f2bf(w);
    }
    lohi[0] = make_ushort4(tmp[0], tmp[1], tmp[2], tmp[3]);
    lohi[1] = make_ushort4(tmp[4], tmp[5], tmp[6], tmp[7]);
    ((ushort4*)Wp)[(size_t)c * 128 + lane * 2 + 0] = lohi[0];
    ((ushort4*)Wp)[(size_t)c * 128 + lane * 2 + 1] = lohi[1];
}

// ---------------- pull-based mean aggregation, bf16 in / bf16 out (fp32 accum) -------------
// one wave per node; lane covers 2 feats (4B packed pair); row = 256B, fully coalesced.

__global__ void aggregate_bf_kernel(const int* __restrict__ rowptr, const int* __restrict__ col,
                                    const unsigned* __restrict__ feat2,  // [NN][64] packed pairs
                                    unsigned* __restrict__ out2) {
    int wid = (blockIdx.x * blockDim.x + threadIdx.x) >> 6;
    int lane = threadIdx.x & 63;
    if (wid >= NN) return;
    int beg = rowptr[wid], end = rowptr[wid + 1];
    float ax = 0.f, ay = 0.f;
    int i = beg;
    for (; i + 4 <= end; i += 4) {
        int s0 = col[i], s1 = col[i + 1], s2 = col[i + 2], s3 = col[i + 3];
        unsigned v0 = feat2[s0 * 64 + lane], v1 = feat2[s1 * 64 + lane];
        unsigned v2 = feat2[s2 * 64 + lane], v3 = feat2[s3 * 64 + lane];
        ax += bfu_lo(v0) + bfu_lo(v1) + bfu_lo(v2) + bfu_lo(v3);
        ay += bfu_hi(v0) + bfu_hi(v1) + bfu_hi(v2) + bfu_hi(v3);
    }
    for (; i < end; i++) {
        unsigned v = feat2[col[i] * 64 + lane];
        ax += bfu_lo(v); ay += bfu_hi(v);
    }
    float inv = (end > beg) ? 1.0f / (float)(end - beg) : 0.0f;
    unsigned o = (unsigned)f2bf(ax * inv) | ((unsigned)f2bf(ay * inv) << 16);
    out2[wid * 64 + lane] = o;
}

// ---------------- MFMA GEMM + fused epilogue (no LDS, no barriers) -------------------------
// C[M,N] = [A0|A1](bf16) @ Wp(packed bf16) + bias; sigmoid + row-L2 (+ log_softmax if FINAL).
// 256 thr = 4 waves; wave owns 16 rows x all N cols. A-frags: row-major 16B loads
// (A[m=lane&15][k=quad*8+j]); all K=256 held in 32 VGPRs, reused across NT col-tiles.
// B-frags: 1KB coalesced chunks from L2-resident Wp. C/D: row=quad*4+reg, col=lane&15 ->
// row reductions are shfl_xor width-16 within the quad.

template <int N, bool FINAL>
__global__ __launch_bounds__(256) void gemm_mfma_kernel(
    const unsigned short* __restrict__ A0, const unsigned short* __restrict__ A1,
    const unsigned short* __restrict__ Wp, const float* __restrict__ bias,
    void* __restrict__ outp, int M) {
    const int NT = N / 16;
    int tid = threadIdx.x, wave = tid >> 6, lane = tid & 63;
    int quad = lane >> 4, col = lane & 15;
    int m_base = blockIdx.x * 64 + wave * 16;
    int row = m_base + col;
    int row_ld = row < M ? row : M - 1;

    // all 8 K-step A-frags (ks 0..3 from A0, 4..7 from A1)
    bf16x8 a[8];
    const uint4* a0p = (const uint4*)(A0 + (size_t)row_ld * 128 + quad * 8);
    const uint4* a1p = (const uint4*)(A1 + (size_t)row_ld * 128 + quad * 8);
#pragma unroll
    for (int ks = 0; ks < 4; ks++) { U16 u; u.u = a0p[ks * 4]; a[ks] = u.v; }
#pragma unroll
    for (int ks = 0; ks < 4; ks++) { U16 u; u.u = a1p[ks * 4]; a[4 + ks] = u.v; }

    f32x4 acc[NT];
#pragma unroll
    for (int nt = 0; nt < NT; nt++) acc[nt] = (f32x4){0.f, 0.f, 0.f, 0.f};

    const uint4* wp = (const uint4*)Wp;  // chunk c: wp[c*64 + lane]
#pragma unroll
    for (int nt = 0; nt < NT; nt++) {
#pragma unroll
        for (int ks = 0; ks < 8; ks++) {
            U16 u; u.u = wp[(size_t)(nt * 8 + ks) * 64 + lane];
            acc[nt] = __builtin_amdgcn_mfma_f32_16x16x32_bf16(a[ks], u.v, acc[nt], 0, 0, 0);
        }
    }

    // epilogue: bias + sigmoid + row L2-norm
    float ssq[4] = {0.f, 0.f, 0.f, 0.f};
#pragma unroll
    for (int nt = 0; nt < NT; nt++) {
        float bv = bias[nt * 16 + col];
#pragma unroll
        for (int r = 0; r < 4; r++) {
            float z = acc[nt][r] + bv;
            float s = 1.0f / (1.0f + __expf(-z));
            acc[nt][r] = s;
            ssq[r] += s * s;
        }
    }
#pragma unroll
    for (int r = 0; r < 4; r++) {
#pragma unroll
        for (int off = 1; off < 16; off <<= 1) ssq[r] += __shfl_xor(ssq[r], off, 16);
        float sc = 1.0f / fmaxf(sqrtf(ssq[r]), 1e-12f);
#pragma unroll
        for (int nt = 0; nt < NT; nt++) acc[nt][r] *= sc;
    }

    if (FINAL) {  // log_softmax per row, then fp32 out
#pragma unroll
        for (int r = 0; r < 4; r++) {
            float mx = -1e30f;
#pragma unroll
            for (int nt = 0; nt < NT; nt++) mx = fmaxf(mx, acc[nt][r]);
#pragma unroll
            for (int off = 1; off < 16; off <<= 1) mx = fmaxf(mx, __shfl_xor(mx, off, 16));
            float se = 0.f;
#pragma unroll
            for (int nt = 0; nt < NT; nt++) se += __expf(acc[nt][r] - mx);
#pragma unroll
            for (int off = 1; off < 16; off <<= 1) se += __shfl_xor(se, off, 16);
            float lse = mx + __logf(se);
#pragma unroll
            for (int nt = 0; nt < NT; nt++) acc[nt][r] -= lse;
        }
        float* op = (float*)outp;
#pragma unroll
        for (int r = 0; r < 4; r++) {
            int m = m_base + quad * 4 + r;
            if (m < M) {
#pragma unroll
                for (int nt = 0; nt < NT; nt++) op[(size_t)m * N + nt * 16 + col] = acc[nt][r];
            }
        }
    } else {  // bf16 out (feeds aggregation 2 + GEMM2 A-operand)
        unsigned short* op = (unsigned short*)outp;
#pragma unroll
        for (int r = 0; r < 4; r++) {
            int m = m_base + quad * 4 + r;
            if (m < M) {
#pragma unroll
                for (int nt = 0; nt < NT; nt++)
                    op[(size_t)m * N + nt * 16 + col] = f2bf(acc[nt][r]);
            }
        }
    }
}

// ---------------- launcher ----------------

extern "C" void kernel_launch(void* const* d_in, const int* in_sizes, int n_in,
                              void* d_out, int out_size, void* d_ws, size_t ws_size,
                              hipStream_t stream) {
    const float* x   = (const float*)d_in[0];
    const int*   ei  = (const int*)d_in[1];
    const float* W1l = (const float*)d_in[2];
    const float* W1r = (const float*)d_in[3];
    const float* b1  = (const float*)d_in[4];
    const float* W2l = (const float*)d_in[5];
    const float* W2r = (const float*)d_in[6];
    const float* b2  = (const float*)d_in[7];
    float* out = (float*)d_out;

    const int* src = ei;
    const int* dst = ei + NE;

    char* ws = (char*)d_ws;
    size_t off = 0;
    auto alloc = [&](size_t bytes) -> void* {
        void* p = ws + off;
        off += (bytes + 255) / 256 * 256;
        return p;
    };
    int* deg        = (int*)alloc((size_t)NN * 4);
    int* rowptr     = (int*)alloc((size_t)(NN + 1) * 4);
    int* cursor     = (int*)alloc((size_t)NN * 4);
    int* col        = (int*)alloc((size_t)NE * 4);
    int* bsum       = (int*)alloc((size_t)NBLK * 4);
    unsigned short* x_bf   = (unsigned short*)alloc((size_t)NN * 128 * 2);
    unsigned short* agg_bf = (unsigned short*)alloc((size_t)NN * 128 * 2);
    unsigned short* h1_bf  = (unsigned short*)alloc((size_t)NN * 128 * 2);
    unsigned short* W1p    = (unsigned short*)alloc((size_t)8 * 8 * 64 * 8 * 2);    // 64KB
    unsigned short* W2p    = (unsigned short*)alloc((size_t)16 * 8 * 64 * 8 * 2);   // 128KB

    // CSR build (graph identical for both layers — build once)
    hipMemsetAsync(deg, 0, (size_t)NN * 4, stream);
    hist_kernel<<<(NE + 255) / 256, 256, 0, stream>>>(dst, deg);
    scan1_kernel<<<NBLK, 256, 0, stream>>>(deg, bsum);
    scan2_kernel<<<NBLK, 256, 0, stream>>>(deg, bsum, rowptr, cursor);
    fill_kernel<<<(NE + 255) / 256, 256, 0, stream>>>(src, dst, cursor, col);

    // prep: cast x to bf16; pack weights into B-frag layout
    cast_bf16_kernel<<<(NN * 128 / 4 + 255) / 256, 256, 0, stream>>>(x, x_bf, NN * 128 / 4);
    pack_w_kernel<128><<<(8 * 8 * 64 + 255) / 256, 256, 0, stream>>>(W1l, W1r, W1p);
    pack_w_kernel<256><<<(16 * 8 * 64 + 255) / 256, 256, 0, stream>>>(W2l, W2r, W2p);

    // layer 1
    aggregate_bf_kernel<<<(NN + 3) / 4, 256, 0, stream>>>(rowptr, col, (const unsigned*)x_bf,
                                                          (unsigned*)agg_bf);
    gemm_mfma_kernel<128, false><<<(NN + 63) / 64, 256, 0, stream>>>(agg_bf, x_bf, W1p, b1,
                                                                     h1_bf, NN);
    // layer 2
    aggregate_bf_kernel<<<(NN + 3) / 4, 256, 0, stream>>>(rowptr, col, (const unsigned*)h1_bf,
                                                          (unsigned*)agg_bf);
    gemm_mfma_kernel<256, true><<<(NN + 63) / 64, 256, 0, stream>>>(agg_bf, h1_bf, W2p, b2,
                                                                    out, NN);
}

// Round 5
// 259.271 us; speedup vs baseline: 2.4569x; 1.2074x over previous
//
#include <hip/hip_runtime.h>

#define NN 50000
#define NE 800000
#define NB 782    // ceil(NN/64) buckets of 64 dst-nodes
#define CAP 1536  // per-bucket edge capacity (avg 1023, sigma 32 -> +16 sigma)

// ---------------- bf16 helpers (bits-level, RNE) ----------------

__device__ __forceinline__ unsigned short f2bf(float f) {
    union { float f; unsigned u; } v; v.f = f;
    unsigned u = v.u;
    return (unsigned short)((u + 0x7fffu + ((u >> 16) & 1u)) >> 16);
}
__device__ __forceinline__ float bfu_lo(unsigned p) {  // low bf16 of packed pair
    union { unsigned u; float f; } v; v.u = p << 16; return v.f;
}
__device__ __forceinline__ float bfu_hi(unsigned p) {  // high bf16 of packed pair
    union { unsigned u; float f; } v; v.u = p & 0xffff0000u; return v.f;
}

typedef __bf16 bf16x8 __attribute__((ext_vector_type(8)));
typedef float f32x4 __attribute__((ext_vector_type(4)));
union U16 { uint4 u; bf16x8 v; };

// ---------------- CSR build: binned scatter (block-private contiguous write runs) ----------
// Replaces hist/scan/fill: old fill did 800k isolated 4B scatters = 51MB of dirty 64B lines.

__global__ __launch_bounds__(512) void binscatter_kernel(const int* __restrict__ src,
                                                         const int* __restrict__ dst,
                                                         int* __restrict__ bcnt,
                                                         unsigned* __restrict__ ebuf) {
    __shared__ int hist[NB];
    __shared__ int base[NB];
    const int BE = 8192;  // edges per block
    int tid = threadIdx.x;
    int e0 = blockIdx.x * BE;
    for (int i = tid; i < NB; i += 512) hist[i] = 0;
    __syncthreads();
    for (int i = tid; i < BE; i += 512) {
        int e = e0 + i;
        if (e < NE) atomicAdd(&hist[dst[e] >> 6], 1);
    }
    __syncthreads();
    for (int i = tid; i < NB; i += 512) {
        int c = hist[i];
        base[i] = c ? atomicAdd(&bcnt[i], c) : 0;  // reserve contiguous run in bucket region
        hist[i] = 0;                                // reuse as cursor
    }
    __syncthreads();
    for (int i = tid; i < BE; i += 512) {
        int e = e0 + i;
        if (e < NE) {
            int d = dst[e], b = d >> 6;
            int slot = base[b] + atomicAdd(&hist[b], 1);
            if (slot < CAP)  // statistically impossible overflow guard
                ebuf[(size_t)b * CAP + slot] = (unsigned)src[e] | ((unsigned)(d & 63) << 16);
        }
    }
}

// exclusive scan of 782 bucket counts -> col/rowptr bases
__global__ __launch_bounds__(1024) void bscan_kernel(const int* __restrict__ bcnt,
                                                     int* __restrict__ boff,
                                                     int* __restrict__ rowptr) {
    __shared__ int sm[1024];
    int tid = threadIdx.x;
    int v = (tid < NB) ? bcnt[tid] : 0;
    sm[tid] = v;
    __syncthreads();
    for (int off = 1; off < 1024; off <<= 1) {
        int t = (tid >= off) ? sm[tid - off] : 0;
        __syncthreads();
        sm[tid] += t;
        __syncthreads();
    }
    if (tid < NB) boff[tid] = sm[tid] - v;  // exclusive
    if (tid == 0) rowptr[NN] = NE;
}

// one block per bucket: LDS degree hist (64 nodes) -> rowptr (coalesced) + col
// (scatter confined to a block-private ~4KB window)
__global__ __launch_bounds__(256) void csr_kernel(const int* __restrict__ bcnt,
                                                  const int* __restrict__ boff,
                                                  const unsigned* __restrict__ ebuf,
                                                  int* __restrict__ rowptr,
                                                  int* __restrict__ col) {
    __shared__ int deg[64];
    __shared__ int cur[64];
    int b = blockIdx.x, tid = threadIdx.x;
    int cnt = bcnt[b], cbase = boff[b];
    if (tid < 64) deg[tid] = 0;
    __syncthreads();
    const unsigned* eb = ebuf + (size_t)b * CAP;
    for (int i = tid; i < cnt; i += 256) atomicAdd(&deg[eb[i] >> 16], 1);
    __syncthreads();
    if (tid == 0) {
        int run = 0;
        for (int j = 0; j < 64; j++) { cur[j] = run; run += deg[j]; }
    }
    __syncthreads();
    int node = b * 64 + tid;
    if (tid < 64 && node < NN) rowptr[node] = cbase + cur[tid];
    __syncthreads();  // rowptr reads of cur[] complete before cursor atomics
    for (int i = tid; i < cnt; i += 256) {
        unsigned e = eb[i];
        int pos = atomicAdd(&cur[e >> 16], 1);
        col[cbase + pos] = (int)(e & 0xffffu);
    }
}

// ---------------- fp32 -> bf16 cast (4 elems/thread) ----------------

__global__ void cast_bf16_kernel(const float* __restrict__ in, unsigned short* __restrict__ outp,
                                 int n4) {
    int i = blockIdx.x * 256 + threadIdx.x;
    if (i < n4) {
        float4 f = ((const float4*)in)[i];
        ushort4 o;
        o.x = f2bf(f.x); o.y = f2bf(f.y); o.z = f2bf(f.z); o.w = f2bf(f.w);
        ((ushort4*)outp)[i] = o;
    }
}

// ---------------- W pack: fp32 [Wl;Wr] (virtual K=256 x N) -> mfma B-frag layout, bf16 -----
// chunk c = nt*8 + ks (1KB each); lane holds B[k = ks*32 + (lane>>4)*8 + j][n = nt*16 + (lane&15)]
// for j=0..7, contiguous 16B per lane -> one coalesced uint4 per wave-chunk in the GEMM.

template <int N>
__global__ void pack_w_kernel(const float* __restrict__ Wl, const float* __restrict__ Wr,
                              unsigned short* __restrict__ Wp) {
    const int NT = N / 16;
    int t = blockIdx.x * 256 + threadIdx.x;  // one thread per (chunk, lane)
    if (t >= NT * 8 * 64) return;
    int lane = t & 63, c = t >> 6;
    int ks = c & 7, nt = c >> 3;
    int n = nt * 16 + (lane & 15);
    int kq = ks * 32 + (lane >> 4) * 8;
    ushort4 lohi[2];
    unsigned short tmp[8];
#pragma unroll
    for (int j = 0; j < 8; j++) {
        int k = kq + j;
        float w = (k < 128) ? Wl[(size_t)k * N + n] : Wr[(size_t)(k - 128) * N + n];
        tmp[j] = f2bf(w);
    }
    lohi[0] = make_ushort4(tmp[0], tmp[1], tmp[2], tmp[3]);
    lohi[1] = make_ushort4(tmp[4], tmp[5], tmp[6], tmp[7]);
    ((ushort4*)Wp)[(size_t)c * 128 + lane * 2 + 0] = lohi[0];
    ((ushort4*)Wp)[(size_t)c * 128 + lane * 2 + 1] = lohi[1];
}

// ---------------- pull-based mean aggregation, bf16 in / bf16 out (fp32 accum) -------------
// one wave per node; lane covers 2 feats (4B packed pair); row = 256B, fully coalesced.

__global__ void aggregate_bf_kernel(const int* __restrict__ rowptr, const int* __restrict__ col,
                                    const unsigned* __restrict__ feat2,  // [NN][64] packed pairs
                                    unsigned* __restrict__ out2) {
    int wid = (blockIdx.x * blockDim.x + threadIdx.x) >> 6;
    int lane = threadIdx.x & 63;
    if (wid >= NN) return;
    int beg = rowptr[wid], end = rowptr[wid + 1];
    float ax = 0.f, ay = 0.f;
    int i = beg;
    for (; i + 4 <= end; i += 4) {
        int s0 = col[i], s1 = col[i + 1], s2 = col[i + 2], s3 = col[i + 3];
        unsigned v0 = feat2[s0 * 64 + lane], v1 = feat2[s1 * 64 + lane];
        unsigned v2 = feat2[s2 * 64 + lane], v3 = feat2[s3 * 64 + lane];
        ax += bfu_lo(v0) + bfu_lo(v1) + bfu_lo(v2) + bfu_lo(v3);
        ay += bfu_hi(v0) + bfu_hi(v1) + bfu_hi(v2) + bfu_hi(v3);
    }
    for (; i < end; i++) {
        unsigned v = feat2[col[i] * 64 + lane];
        ax += bfu_lo(v); ay += bfu_hi(v);
    }
    float inv = (end > beg) ? 1.0f / (float)(end - beg) : 0.0f;
    unsigned o = (unsigned)f2bf(ax * inv) | ((unsigned)f2bf(ay * inv) << 16);
    out2[wid * 64 + lane] = o;
}

// ---------------- MFMA GEMM + fused epilogue (no LDS, no barriers) -------------------------
// C[M,N] = [A0|A1](bf16) @ Wp(packed bf16) + bias; sigmoid + row-L2 (+ log_softmax if FINAL).
// 256 thr = 4 waves; wave owns 16 rows x all N cols. A-frags: row-major 16B loads
// (A[m=lane&15][k=quad*8+j]); all K=256 held in 32 VGPRs, reused across NT col-tiles.
// B-frags: 1KB coalesced chunks from L2-resident Wp. C/D: row=quad*4+reg, col=lane&15 ->
// row reductions are shfl_xor width-16 within the quad.

template <int N, bool FINAL>
__global__ __launch_bounds__(256) void gemm_mfma_kernel(
    const unsigned short* __restrict__ A0, const unsigned short* __restrict__ A1,
    const unsigned short* __restrict__ Wp, const float* __restrict__ bias,
    void* __restrict__ outp, int M) {
    const int NT = N / 16;
    int tid = threadIdx.x, wave = tid >> 6, lane = tid & 63;
    int quad = lane >> 4, col = lane & 15;
    int m_base = blockIdx.x * 64 + wave * 16;
    int row = m_base + col;
    int row_ld = row < M ? row : M - 1;

    // all 8 K-step A-frags (ks 0..3 from A0, 4..7 from A1)
    bf16x8 a[8];
    const uint4* a0p = (const uint4*)(A0 + (size_t)row_ld * 128 + quad * 8);
    const uint4* a1p = (const uint4*)(A1 + (size_t)row_ld * 128 + quad * 8);
#pragma unroll
    for (int ks = 0; ks < 4; ks++) { U16 u; u.u = a0p[ks * 4]; a[ks] = u.v; }
#pragma unroll
    for (int ks = 0; ks < 4; ks++) { U16 u; u.u = a1p[ks * 4]; a[4 + ks] = u.v; }

    f32x4 acc[NT];
#pragma unroll
    for (int nt = 0; nt < NT; nt++) acc[nt] = (f32x4){0.f, 0.f, 0.f, 0.f};

    const uint4* wp = (const uint4*)Wp;  // chunk c: wp[c*64 + lane]
#pragma unroll
    for (int nt = 0; nt < NT; nt++) {
#pragma unroll
        for (int ks = 0; ks < 8; ks++) {
            U16 u; u.u = wp[(size_t)(nt * 8 + ks) * 64 + lane];
            acc[nt] = __builtin_amdgcn_mfma_f32_16x16x32_bf16(a[ks], u.v, acc[nt], 0, 0, 0);
        }
    }

    // epilogue: bias + sigmoid + row L2-norm
    float ssq[4] = {0.f, 0.f, 0.f, 0.f};
#pragma unroll
    for (int nt = 0; nt < NT; nt++) {
        float bv = bias[nt * 16 + col];
#pragma unroll
        for (int r = 0; r < 4; r++) {
            float z = acc[nt][r] + bv;
            float s = 1.0f / (1.0f + __expf(-z));
            acc[nt][r] = s;
            ssq[r] += s * s;
        }
    }
#pragma unroll
    for (int r = 0; r < 4; r++) {
#pragma unroll
        for (int off = 1; off < 16; off <<= 1) ssq[r] += __shfl_xor(ssq[r], off, 16);
        float sc = 1.0f / fmaxf(sqrtf(ssq[r]), 1e-12f);
#pragma unroll
        for (int nt = 0; nt < NT; nt++) acc[nt][r] *= sc;
    }

    if (FINAL) {  // log_softmax per row, then fp32 out
#pragma unroll
        for (int r = 0; r < 4; r++) {
            float mx = -1e30f;
#pragma unroll
            for (int nt = 0; nt < NT; nt++) mx = fmaxf(mx, acc[nt][r]);
#pragma unroll
            for (int off = 1; off < 16; off <<= 1) mx = fmaxf(mx, __shfl_xor(mx, off, 16));
            float se = 0.f;
#pragma unroll
            for (int nt = 0; nt < NT; nt++) se += __expf(acc[nt][r] - mx);
#pragma unroll
            for (int off = 1; off < 16; off <<= 1) se += __shfl_xor(se, off, 16);
            float lse = mx + __logf(se);
#pragma unroll
            for (int nt = 0; nt < NT; nt++) acc[nt][r] -= lse;
        }
        float* op = (float*)outp;
#pragma unroll
        for (int r = 0; r < 4; r++) {
            int m = m_base + quad * 4 + r;
            if (m < M) {
#pragma unroll
                for (int nt = 0; nt < NT; nt++) op[(size_t)m * N + nt * 16 + col] = acc[nt][r];
            }
        }
    } else {  // bf16 out (feeds aggregation 2 + GEMM2 A-operand)
        unsigned short* op = (unsigned short*)outp;
#pragma unroll
        for (int r = 0; r < 4; r++) {
            int m = m_base + quad * 4 + r;
            if (m < M) {
#pragma unroll
                for (int nt = 0; nt < NT; nt++)
                    op[(size_t)m * N + nt * 16 + col] = f2bf(acc[nt][r]);
            }
        }
    }
}

// ---------------- launcher ----------------

extern "C" void kernel_launch(void* const* d_in, const int* in_sizes, int n_in,
                              void* d_out, int out_size, void* d_ws, size_t ws_size,
                              hipStream_t stream) {
    const float* x   = (const float*)d_in[0];
    const int*   ei  = (const int*)d_in[1];
    const float* W1l = (const float*)d_in[2];
    const float* W1r = (const float*)d_in[3];
    const float* b1  = (const float*)d_in[4];
    const float* W2l = (const float*)d_in[5];
    const float* W2r = (const float*)d_in[6];
    const float* b2  = (const float*)d_in[7];
    float* out = (float*)d_out;

    const int* src = ei;
    const int* dst = ei + NE;

    char* ws = (char*)d_ws;
    size_t off = 0;
    auto alloc = [&](size_t bytes) -> void* {
        void* p = ws + off;
        off += (bytes + 255) / 256 * 256;
        return p;
    };
    int* rowptr     = (int*)alloc((size_t)(NN + 1) * 4);
    int* col        = (int*)alloc((size_t)NE * 4);
    int* bcnt       = (int*)alloc((size_t)NB * 4);
    int* boff       = (int*)alloc((size_t)NB * 4);
    unsigned* ebuf  = (unsigned*)alloc((size_t)NB * CAP * 4);  // 4.8MB
    unsigned short* x_bf   = (unsigned short*)alloc((size_t)NN * 128 * 2);
    unsigned short* agg_bf = (unsigned short*)alloc((size_t)NN * 128 * 2);
    unsigned short* h1_bf  = (unsigned short*)alloc((size_t)NN * 128 * 2);
    unsigned short* W1p    = (unsigned short*)alloc((size_t)8 * 8 * 64 * 8 * 2);    // 64KB
    unsigned short* W2p    = (unsigned short*)alloc((size_t)16 * 8 * 64 * 8 * 2);   // 128KB

    // CSR build (graph identical for both layers — build once)
    hipMemsetAsync(bcnt, 0, (size_t)NB * 4, stream);
    binscatter_kernel<<<(NE + 8191) / 8192, 512, 0, stream>>>(src, dst, bcnt, ebuf);
    bscan_kernel<<<1, 1024, 0, stream>>>(bcnt, boff, rowptr);
    csr_kernel<<<NB, 256, 0, stream>>>(bcnt, boff, ebuf, rowptr, col);

    // prep: cast x to bf16; pack weights into B-frag layout
    cast_bf16_kernel<<<(NN * 128 / 4 + 255) / 256, 256, 0, stream>>>(x, x_bf, NN * 128 / 4);
    pack_w_kernel<128><<<(8 * 8 * 64 + 255) / 256, 256, 0, stream>>>(W1l, W1r, W1p);
    pack_w_kernel<256><<<(16 * 8 * 64 + 255) / 256, 256, 0, stream>>>(W2l, W2r, W2p);

    // layer 1
    aggregate_bf_kernel<<<(NN + 3) / 4, 256, 0, stream>>>(rowptr, col, (const unsigned*)x_bf,
                                                          (unsigned*)agg_bf);
    gemm_mfma_kernel<128, false><<<(NN + 63) / 64, 256, 0, stream>>>(agg_bf, x_bf, W1p, b1,
                                                                     h1_bf, NN);
    // layer 2
    aggregate_bf_kernel<<<(NN + 3) / 4, 256, 0, stream>>>(rowptr, col, (const unsigned*)h1_bf,
                                                          (unsigned*)agg_bf);
    gemm_mfma_kernel<256, true><<<(NN + 63) / 64, 256, 0, stream>>>(agg_bf, h1_bf, W2p, b2,
                                                                    out, NN);
}

// Round 7
// 253.373 us; speedup vs baseline: 2.5141x; 1.0233x over previous
//
#include <hip/hip_runtime.h>

#define NN 50000
#define NE 800000
#define NB 782    // ceil(NN/64) buckets of 64 dst-nodes
#define CAP 1536  // per-bucket edge capacity (avg 1023, sigma 32 -> +16 sigma)

// ---------------- bf16 helpers (bits-level, RNE) ----------------

__device__ __forceinline__ unsigned short f2bf(float f) {
    union { float f; unsigned u; } v; v.f = f;
    unsigned u = v.u;
    return (unsigned short)((u + 0x7fffu + ((u >> 16) & 1u)) >> 16);
}
__device__ __forceinline__ float bfu_lo(unsigned p) {  // low bf16 of packed pair
    union { unsigned u; float f; } v; v.u = p << 16; return v.f;
}
__device__ __forceinline__ float bfu_hi(unsigned p) {  // high bf16 of packed pair
    union { unsigned u; float f; } v; v.u = p & 0xffff0000u; return v.f;
}

typedef __bf16 bf16x8 __attribute__((ext_vector_type(8)));
typedef float f32x4 __attribute__((ext_vector_type(4)));
union U16 { uint4 u; bf16x8 v; };

// ---------------- CSR build: binned scatter (block-private contiguous write runs) ----------
// 98 blocks x 8192 edges: ~10.5 edges/bucket/block -> ~42B runs, line-dense ebuf writes.

__global__ __launch_bounds__(512) void binscatter_kernel(const int* __restrict__ src,
                                                         const int* __restrict__ dst,
                                                         int* __restrict__ bcnt,
                                                         unsigned* __restrict__ ebuf) {
    __shared__ int hist[NB];
    __shared__ int base[NB];
    const int BE = 8192;  // edges per block
    int tid = threadIdx.x;
    int e0 = blockIdx.x * BE;
    for (int i = tid; i < NB; i += 512) hist[i] = 0;
    __syncthreads();
    for (int i = tid; i < BE; i += 512) {
        int e = e0 + i;
        if (e < NE) atomicAdd(&hist[dst[e] >> 6], 1);
    }
    __syncthreads();
    for (int i = tid; i < NB; i += 512) {
        int c = hist[i];
        base[i] = c ? atomicAdd(&bcnt[i], c) : 0;  // reserve contiguous run in bucket region
        hist[i] = 0;                                // reuse as cursor
    }
    __syncthreads();
    for (int i = tid; i < BE; i += 512) {
        int e = e0 + i;
        if (e < NE) {
            int d = dst[e], b = d >> 6;
            int slot = base[b] + atomicAdd(&hist[b], 1);
            if (slot < CAP)  // statistically impossible overflow guard
                ebuf[(size_t)b * CAP + slot] = (unsigned)src[e] | ((unsigned)(d & 63) << 16);
        }
    }
}

// one block per bucket: own prefix over bcnt + LDS degree hist (64 nodes) -> rowptr + col
// (scatter confined to a block-private ~4KB window; bscan kernel folded in here)
__global__ __launch_bounds__(256) void csr_kernel(const int* __restrict__ bcnt,
                                                  const unsigned* __restrict__ ebuf,
                                                  int* __restrict__ rowptr,
                                                  int* __restrict__ col) {
    __shared__ int red[256];
    __shared__ int deg[64];
    __shared__ int cur[64];
    __shared__ int cbase_s;
    int b = blockIdx.x, tid = threadIdx.x;
    // exclusive prefix of bucket counts: sum bcnt[0..b) (all L2-hit)
    int s = 0;
    for (int i = tid; i < b; i += 256) s += bcnt[i];
    red[tid] = s;
    if (tid < 64) deg[tid] = 0;
    __syncthreads();
    for (int off = 128; off; off >>= 1) {
        if (tid < off) red[tid] += red[tid + off];
        __syncthreads();
    }
    if (tid == 0) cbase_s = red[0];
    __syncthreads();
    int cnt = bcnt[b], cbase = cbase_s;
    if (cnt > CAP) cnt = CAP;  // defensive: never read past bucket window
    const unsigned* eb = ebuf + (size_t)b * CAP;
    for (int i = tid; i < cnt; i += 256) atomicAdd(&deg[(eb[i] >> 16) & 63], 1);
    __syncthreads();
    if (tid == 0) {
        int run = 0;
        for (int j = 0; j < 64; j++) { cur[j] = run; run += deg[j]; }
    }
    __syncthreads();
    int node = b * 64 + tid;
    if (tid < 64 && node < NN) rowptr[node] = cbase + cur[tid];
    if (b == NB - 1 && tid == 0) rowptr[NN] = NE;
    __syncthreads();  // rowptr reads of cur[] complete before cursor atomics
    for (int i = tid; i < cnt; i += 256) {
        unsigned e = eb[i];
        int pos = atomicAdd(&cur[(e >> 16) & 63], 1);
        col[cbase + pos] = (int)(e & 0xffffu);
    }
}

// ---------------- fp32 -> bf16 cast (4 elems/thread) ----------------

__global__ void cast_bf16_kernel(const float* __restrict__ in, unsigned short* __restrict__ outp,
                                 int n4) {
    int i = blockIdx.x * 256 + threadIdx.x;
    if (i < n4) {
        float4 f = ((const float4*)in)[i];
        ushort4 o;
        o.x = f2bf(f.x); o.y = f2bf(f.y); o.z = f2bf(f.z); o.w = f2bf(f.w);
        ((ushort4*)outp)[i] = o;
    }
}

// ---------------- W pack: fp32 [Wl;Wr] (virtual K=256 x N) -> mfma B-frag layout, bf16 -----
// chunk c = nt*8 + ks (1KB each); lane holds B[k = ks*32 + (lane>>4)*8 + j][n = nt*16 + (lane&15)]
// for j=0..7, contiguous 16B per lane -> one coalesced uint4 per wave-chunk in the GEMM.

template <int N>
__device__ __forceinline__ void pack_one(const float* __restrict__ Wl,
                                         const float* __restrict__ Wr,
                                         unsigned short* __restrict__ Wp, int t) {
    int lane = t & 63, c = t >> 6;
    int ks = c & 7, nt = c >> 3;
    int n = nt * 16 + (lane & 15);
    int kq = ks * 32 + (lane >> 4) * 8;
    unsigned short tmp[8];
#pragma unroll
    for (int j = 0; j < 8; j++) {
        int k = kq + j;
        float w = (k < 128) ? Wl[(size_t)k * N + n] : Wr[(size_t)(k - 128) * N + n];
        tmp[j] = f2bf(w);
    }
    ((ushort4*)Wp)[(size_t)c * 128 + lane * 2 + 0] = make_ushort4(tmp[0], tmp[1], tmp[2], tmp[3]);
    ((ushort4*)Wp)[(size_t)c * 128 + lane * 2 + 1] = make_ushort4(tmp[4], tmp[5], tmp[6], tmp[7]);
}

__global__ void pack_both_kernel(const float* __restrict__ W1l, const float* __restrict__ W1r,
                                 unsigned short* __restrict__ W1p,
                                 const float* __restrict__ W2l, const float* __restrict__ W2r,
                                 unsigned short* __restrict__ W2p) {
    int t = blockIdx.x * 256 + threadIdx.x;
    if (t < 8 * 8 * 64) pack_one<128>(W1l, W1r, W1p, t);
    else if (t < 8 * 8 * 64 + 16 * 8 * 64) pack_one<256>(W2l, W2r, W2p, t - 8 * 8 * 64);
}

// ---------------- pull-based mean aggregation, bf16, 4-neighbor-vectorized gather ----------
// one wave per node; lane-group g=lane>>4 targets neighbor i+g, each lane loads uint4 (16B):
// 4 x 256B rows in flight per load instruction (4x MLP vs 4B/lane). Cross-group combine via
// shfl_xor(16,32); lanes 0..15 write the 256B output row.

__global__ void aggregate_bf_kernel(const int* __restrict__ rowptr, const int* __restrict__ col,
                                    const uint4* __restrict__ feat4,  // [NN][16] 16B chunks
                                    uint4* __restrict__ out4) {
    int wid = (blockIdx.x * blockDim.x + threadIdx.x) >> 6;
    int lane = threadIdx.x & 63;
    if (wid >= NN) return;
    int beg = rowptr[wid], end = rowptr[wid + 1];
    int g = lane >> 4, c16 = lane & 15;
    float acc[8];
#pragma unroll
    for (int j = 0; j < 8; j++) acc[j] = 0.f;
    for (int i = beg; i < end; i += 4) {
        int idx = i + g;
        if (idx < end) {  // exec-masked tail: no wasted loads
            int s = col[idx];
            uint4 v = feat4[(size_t)s * 16 + c16];
            acc[0] += bfu_lo(v.x); acc[1] += bfu_hi(v.x);
            acc[2] += bfu_lo(v.y); acc[3] += bfu_hi(v.y);
            acc[4] += bfu_lo(v.z); acc[5] += bfu_hi(v.z);
            acc[6] += bfu_lo(v.w); acc[7] += bfu_hi(v.w);
        }
    }
#pragma unroll
    for (int j = 0; j < 8; j++) {
        acc[j] += __shfl_xor(acc[j], 16);
        acc[j] += __shfl_xor(acc[j], 32);
    }
    if (g == 0) {
        float inv = (end > beg) ? 1.0f / (float)(end - beg) : 0.0f;
        uint4 o;
        o.x = (unsigned)f2bf(acc[0] * inv) | ((unsigned)f2bf(acc[1] * inv) << 16);
        o.y = (unsigned)f2bf(acc[2] * inv) | ((unsigned)f2bf(acc[3] * inv) << 16);
        o.z = (unsigned)f2bf(acc[4] * inv) | ((unsigned)f2bf(acc[5] * inv) << 16);
        o.w = (unsigned)f2bf(acc[6] * inv) | ((unsigned)f2bf(acc[7] * inv) << 16);
        out4[(size_t)wid * 16 + c16] = o;
    }
}

// ---------------- MFMA GEMM + fused epilogue (no LDS, no barriers) -------------------------
// R5-proven version (single row-group). C[M,N] = [A0|A1](bf16) @ Wp + bias; sigmoid +
// row-L2 (+ log_softmax if FINAL). 256 thr = 4 waves; wave owns 16 rows x all N cols.
// A-frags: row-major 16B loads (A[m=lane&15][k=quad*8+j]); K=256 resident in 32 VGPRs.
// C/D: row=quad*4+reg, col=lane&15 -> row reductions are shfl_xor width-16 within the quad.

template <int N, bool FINAL>
__global__ __launch_bounds__(256) void gemm_mfma_kernel(
    const unsigned short* __restrict__ A0, const unsigned short* __restrict__ A1,
    const unsigned short* __restrict__ Wp, const float* __restrict__ bias,
    void* __restrict__ outp, int M) {
    const int NT = N / 16;
    int tid = threadIdx.x, wave = tid >> 6, lane = tid & 63;
    int quad = lane >> 4, col = lane & 15;
    int m_base = blockIdx.x * 64 + wave * 16;
    int row = m_base + col;
    int row_ld = row < M ? row : M - 1;

    // all 8 K-step A-frags (ks 0..3 from A0, 4..7 from A1)
    bf16x8 a[8];
    const uint4* a0p = (const uint4*)(A0 + (size_t)row_ld * 128 + quad * 8);
    const uint4* a1p = (const uint4*)(A1 + (size_t)row_ld * 128 + quad * 8);
#pragma unroll
    for (int ks = 0; ks < 4; ks++) { U16 u; u.u = a0p[ks * 4]; a[ks] = u.v; }
#pragma unroll
    for (int ks = 0; ks < 4; ks++) { U16 u; u.u = a1p[ks * 4]; a[4 + ks] = u.v; }

    f32x4 acc[NT];
#pragma unroll
    for (int nt = 0; nt < NT; nt++) acc[nt] = (f32x4){0.f, 0.f, 0.f, 0.f};

    const uint4* wp = (const uint4*)Wp;  // chunk c: wp[c*64 + lane]
#pragma unroll
    for (int nt = 0; nt < NT; nt++) {
#pragma unroll
        for (int ks = 0; ks < 8; ks++) {
            U16 u; u.u = wp[(size_t)(nt * 8 + ks) * 64 + lane];
            acc[nt] = __builtin_amdgcn_mfma_f32_16x16x32_bf16(a[ks], u.v, acc[nt], 0, 0, 0);
        }
    }

    // epilogue: bias + sigmoid + row L2-norm
    float ssq[4] = {0.f, 0.f, 0.f, 0.f};
#pragma unroll
    for (int nt = 0; nt < NT; nt++) {
        float bv = bias[nt * 16 + col];
#pragma unroll
        for (int r = 0; r < 4; r++) {
            float z = acc[nt][r] + bv;
            float s = 1.0f / (1.0f + __expf(-z));
            acc[nt][r] = s;
            ssq[r] += s * s;
        }
    }
#pragma unroll
    for (int r = 0; r < 4; r++) {
#pragma unroll
        for (int off = 1; off < 16; off <<= 1) ssq[r] += __shfl_xor(ssq[r], off, 16);
        float sc = 1.0f / fmaxf(sqrtf(ssq[r]), 1e-12f);
#pragma unroll
        for (int nt = 0; nt < NT; nt++) acc[nt][r] *= sc;
    }

    if (FINAL) {  // log_softmax per row, then fp32 out
#pragma unroll
        for (int r = 0; r < 4; r++) {
            float mx = -1e30f;
#pragma unroll
            for (int nt = 0; nt < NT; nt++) mx = fmaxf(mx, acc[nt][r]);
#pragma unroll
            for (int off = 1; off < 16; off <<= 1) mx = fmaxf(mx, __shfl_xor(mx, off, 16));
            float se = 0.f;
#pragma unroll
            for (int nt = 0; nt < NT; nt++) se += __expf(acc[nt][r] - mx);
#pragma unroll
            for (int off = 1; off < 16; off <<= 1) se += __shfl_xor(se, off, 16);
            float lse = mx + __logf(se);
#pragma unroll
            for (int nt = 0; nt < NT; nt++) acc[nt][r] -= lse;
        }
        float* op = (float*)outp;
#pragma unroll
        for (int r = 0; r < 4; r++) {
            int m = m_base + quad * 4 + r;
            if (m < M) {
#pragma unroll
                for (int nt = 0; nt < NT; nt++) op[(size_t)m * N + nt * 16 + col] = acc[nt][r];
            }
        }
    } else {  // bf16 out (feeds aggregation 2 + GEMM2 A-operand)
        unsigned short* op = (unsigned short*)outp;
#pragma unroll
        for (int r = 0; r < 4; r++) {
            int m = m_base + quad * 4 + r;
            if (m < M) {
#pragma unroll
                for (int nt = 0; nt < NT; nt++)
                    op[(size_t)m * N + nt * 16 + col] = f2bf(acc[nt][r]);
            }
        }
    }
}

// ---------------- launcher ----------------

extern "C" void kernel_launch(void* const* d_in, const int* in_sizes, int n_in,
                              void* d_out, int out_size, void* d_ws, size_t ws_size,
                              hipStream_t stream) {
    const float* x   = (const float*)d_in[0];
    const int*   ei  = (const int*)d_in[1];
    const float* W1l = (const float*)d_in[2];
    const float* W1r = (const float*)d_in[3];
    const float* b1  = (const float*)d_in[4];
    const float* W2l = (const float*)d_in[5];
    const float* W2r = (const float*)d_in[6];
    const float* b2  = (const float*)d_in[7];
    float* out = (float*)d_out;

    const int* src = ei;
    const int* dst = ei + NE;

    char* ws = (char*)d_ws;
    size_t off = 0;
    auto alloc = [&](size_t bytes) -> void* {
        void* p = ws + off;
        off += (bytes + 255) / 256 * 256;
        return p;
    };
    int* rowptr     = (int*)alloc((size_t)(NN + 1) * 4);
    int* col        = (int*)alloc((size_t)NE * 4);
    int* bcnt       = (int*)alloc((size_t)NB * 4);
    unsigned* ebuf  = (unsigned*)alloc((size_t)NB * CAP * 4);  // 4.8MB
    unsigned short* x_bf   = (unsigned short*)alloc((size_t)NN * 128 * 2);
    unsigned short* agg_bf = (unsigned short*)alloc((size_t)NN * 128 * 2);
    unsigned short* h1_bf  = (unsigned short*)alloc((size_t)NN * 128 * 2);
    unsigned short* W1p    = (unsigned short*)alloc((size_t)8 * 8 * 64 * 8 * 2);    // 64KB
    unsigned short* W2p    = (unsigned short*)alloc((size_t)16 * 8 * 64 * 8 * 2);   // 128KB

    // CSR build (graph identical for both layers — build once)
    hipMemsetAsync(bcnt, 0, (size_t)NB * 4, stream);
    binscatter_kernel<<<(NE + 8191) / 8192, 512, 0, stream>>>(src, dst, bcnt, ebuf);
    csr_kernel<<<NB, 256, 0, stream>>>(bcnt, ebuf, rowptr, col);

    // prep: cast x to bf16; pack both weight sets into B-frag layout
    cast_bf16_kernel<<<(NN * 128 / 4 + 255) / 256, 256, 0, stream>>>(x, x_bf, NN * 128 / 4);
    pack_both_kernel<<<(24 * 8 * 64 + 255) / 256, 256, 0, stream>>>(W1l, W1r, W1p, W2l, W2r, W2p);

    // layer 1
    aggregate_bf_kernel<<<(NN + 3) / 4, 256, 0, stream>>>(rowptr, col, (const uint4*)x_bf,
                                                          (uint4*)agg_bf);
    gemm_mfma_kernel<128, false><<<(NN + 63) / 64, 256, 0, stream>>>(agg_bf, x_bf, W1p, b1,
                                                                     h1_bf, NN);
    // layer 2
    aggregate_bf_kernel<<<(NN + 3) / 4, 256, 0, stream>>>(rowptr, col, (const uint4*)h1_bf,
                                                          (uint4*)agg_bf);
    gemm_mfma_kernel<256, true><<<(NN + 63) / 64, 256, 0, stream>>>(agg_bf, h1_bf, W2p, b2,
                                                                    out, NN);
}